// Round 16
// baseline (921.480 us; speedup 1.0000x reference)
//
#include <hip/hip_runtime.h>
#include <hip/hip_bf16.h>
#include <stdint.h>

typedef __attribute__((ext_vector_type(4))) float f32x4;
typedef __attribute__((ext_vector_type(8))) short short8;
typedef __attribute__((ext_vector_type(4))) short short4v;

#define CDIV(a, b) (((a) + (b) - 1) / (b))

__device__ __forceinline__ unsigned short f2bf(float x) {
  union { float f; unsigned int u; } c; c.f = x;
  unsigned int r = c.u + 0x7FFFu + ((c.u >> 16) & 1u);   // round-to-nearest-even
  return (unsigned short)(r >> 16);
}
__device__ __forceinline__ unsigned short f2bf_hw(float x) {
  __hip_bfloat16 h = __float2bfloat16(x);                // pairs fuse into v_cvt_pk_bf16_f32
  unsigned short u; __builtin_memcpy(&u, &h, 2); return u;
}
__device__ __forceinline__ float bf2f(unsigned short b) {
  union { unsigned int u; float f; } c; c.u = (unsigned int)b << 16; return c.f;
}

// async global->LDS, 16B per lane; LDS dest must be wave-uniform base + lane*16 (linear)
__device__ __forceinline__ void gl2lds16(const void* g, void* lds) {
  __builtin_amdgcn_global_load_lds(
      reinterpret_cast<const __attribute__((address_space(1))) unsigned int*>(
          reinterpret_cast<uintptr_t>(g)),
      reinterpret_cast<__attribute__((address_space(3))) unsigned int*>(
          reinterpret_cast<uintptr_t>(lds)),
      16, 0, 0);
}

// ---------------- weight transpose: W[K][N] f32 -> Wt[N][Kpad] bf16, zero-padded ----------------
__global__ void transpose_w(const float* __restrict__ W, unsigned short* __restrict__ Wt,
                            int K, int N, int Kpad) {
  __shared__ float tile[32][33];
  int kb = blockIdx.x * 32, nb = blockIdx.y * 32;
  int tx = threadIdx.x & 31, ty = threadIdx.x >> 5;  // 256 threads = 32x8
  for (int r = ty; r < 32; r += 8) {
    int k = kb + r, n = nb + tx;
    tile[r][tx] = (k < K && n < N) ? W[(size_t)k * N + n] : 0.f;
  }
  __syncthreads();
  for (int r = ty; r < 32; r += 8) {
    int n = nb + r, k = kb + tx;
    if (n < N && k < Kpad) Wt[(size_t)n * Kpad + k] = f2bf(tile[tx][r]);
  }
}

// ---------------- graph prep (consolidated: both graphs per launch) ----------------
__global__ void prep_init(int* __restrict__ dA, int* __restrict__ dB,
                          int* __restrict__ cA, int* __restrict__ cB, int n) {
  int i = blockIdx.x * blockDim.x + threadIdx.x;
  if (i < n) { dA[i] = 1; dB[i] = 1; cA[i] = 0; cB[i] = 0; }   // deg=1 (self-loop), cursor=0
}

__global__ void deg_hist_both(const int* __restrict__ eiA, int EA, int* __restrict__ degA,
                              const int* __restrict__ eiB, int EB, int* __restrict__ degB, int n) {
  int e = blockIdx.x * blockDim.x + threadIdx.x;
  if (e < EA) {
    unsigned int d = (unsigned int)eiA[(size_t)EA + e];
    if (d < (unsigned int)n) atomicAdd(&degA[d], 1);
  } else if (e < EA + EB) {
    int e2 = e - EA;
    unsigned int d = (unsigned int)eiB[(size_t)EB + e2];
    if (d < (unsigned int)n) atomicAdd(&degB[d], 1);
  }
}

__global__ void dinv_both(const int* __restrict__ dA, float* __restrict__ vA,
                          const int* __restrict__ dB, float* __restrict__ vB, int n) {
  int i = blockIdx.x * blockDim.x + threadIdx.x;
  if (i < n) { vA[i] = rsqrtf((float)dA[i]); vB[i] = rsqrtf((float)dB[i]); }
}

// exclusive scan of (deg-1) -> row_ptr[0..n]; blockIdx.x selects graph
__global__ void scan_rowptr_dual(const int* __restrict__ degA, int* __restrict__ rpA,
                                 const int* __restrict__ degB, int* __restrict__ rpB, int n) {
  const int* deg = (blockIdx.x == 0) ? degA : degB;
  int* rp = (blockIdx.x == 0) ? rpA : rpB;
  __shared__ int wsum[16];
  __shared__ int carry_s;
  const int tid = threadIdx.x, lane = tid & 63, w = tid >> 6;
  if (tid == 0) carry_s = 0;
  __syncthreads();
  for (int base = 0; base < n; base += 1024) {
    int i = base + tid;
    int d = (i < n) ? (deg[i] - 1) : 0;
    int v = d;
    #pragma unroll
    for (int off = 1; off < 64; off <<= 1) {
      int t = __shfl_up(v, off, 64);
      if (lane >= off) v += t;
    }
    if (lane == 63) wsum[w] = v;
    __syncthreads();
    int carry = carry_s;
    if (w == 0) {
      int s = (lane < 16) ? wsum[lane] : 0;
      #pragma unroll
      for (int off = 1; off < 16; off <<= 1) {
        int t = __shfl_up(s, off, 64);
        if (lane >= off) s += t;
      }
      if (lane < 16) wsum[lane] = s;
    }
    __syncthreads();
    int woff = (w > 0) ? wsum[w - 1] : 0;
    if (i < n) rp[i] = carry + woff + v - d;
    if (tid == 0) carry_s = carry + wsum[15];
    __syncthreads();
  }
  if (threadIdx.x == 0) rp[n] = carry_s;
}

__global__ void csr_fill_both(const int* __restrict__ eiA, int EA, const int* __restrict__ rpA,
                              int* __restrict__ curA, const float* __restrict__ dvA,
                              int* __restrict__ csA, float* __restrict__ cnA,
                              const int* __restrict__ eiB, int EB, const int* __restrict__ rpB,
                              int* __restrict__ curB, const float* __restrict__ dvB,
                              int* __restrict__ csB, float* __restrict__ cnB, int n) {
  int e = blockIdx.x * blockDim.x + threadIdx.x;
  if (e < EA) {
    unsigned int s = (unsigned int)eiA[e];
    unsigned int d = (unsigned int)eiA[(size_t)EA + e];
    if (s < (unsigned int)n && d < (unsigned int)n) {
      int pos = rpA[d] + atomicAdd(&curA[d], 1);
      csA[pos] = (int)s;
      cnA[pos] = dvA[s] * dvA[d];
    }
  } else if (e < EA + EB) {
    int e2 = e - EA;
    unsigned int s = (unsigned int)eiB[e2];
    unsigned int d = (unsigned int)eiB[(size_t)EB + e2];
    if (s < (unsigned int)n && d < (unsigned int)n) {
      int pos = rpB[d] + atomicAdd(&curB[d], 1);
      csB[pos] = (int)s;
      cnB[pos] = dvB[s] * dvB[d];
    }
  }
}

// ---------------- gemm_pair: TWO independent GEMMs, GROUP-INTERLEAVED (XCD-preserving) ----
// bid0: xcd = bid0&7 (hardware XCD digit, PRESERVED), g = bid0>>3, job = g&1,
// per-job bid = ((g>>1)<<3)|xcd  -- bijective onto [0,G) per job, keeps bid%8 == HW XCD.
// Short-K job's blocks finish early and are replaced -> mixed-phase blocks per CU
// throughout the dispatch (vs r15 concatenation where overlap was tail-only).
// Body = r8-proven gemm7. AMODE 1: A bf16 via gl2lds. AMODE 3: A f32 RAW via gl2lds,
// bf16 cvt at fragment read; K-tail reg-staged zero-masked (K%4==0).
template<int BM, int BN, int TH, int NT_N, int AMODE, bool ADD_BIAS, bool DO_RELU>
__global__ __launch_bounds__(TH, 2)
void gemm_pair(const void* __restrict__ A0, const unsigned short* __restrict__ Bt0,
               const float* __restrict__ b0, unsigned short* __restrict__ C0, int K0, int Kp0,
               const void* __restrict__ A1, const unsigned short* __restrict__ Bt1,
               const float* __restrict__ b1, unsigned short* __restrict__ C1, int K1, int Kp1,
               int NT_M, int M, int N) {
  constexpr int BK = 64;
  constexpr int WN = TH / 64;
  constexpr int WCOLS = BN / WN;
  constexpr int FM = BM / 16, FN = WCOLS / 16;
  constexpr int BIT  = (BN * 8) / TH;
  constexpr int AIT1 = (BM * 8) / TH;
  constexpr int AIT3 = (BM * 16) / TH;
  constexpr int LOGN = (NT_N == 4) ? 2 : (NT_N == 2 ? 1 : 0);

  const int bid0 = blockIdx.x;
  const int xcd = bid0 & 7;
  const int g = bid0 >> 3;
  const bool j1 = (g & 1) != 0;
  const int bid = ((g >> 1) << 3) | xcd;

  const void* Av = j1 ? A1 : A0;
  const unsigned short* Bt = j1 ? Bt1 : Bt0;
  const float* bias = j1 ? b1 : b0;
  unsigned short* C = j1 ? C1 : C0;
  const int K = j1 ? K1 : K0;
  const int Kpad = j1 ? Kp1 : Kp0;

  const int j = bid >> 3;
  const int per = (NT_M + 7) >> 3;
  const int mt = xcd * per + (j >> LOGN);
  const int nt = j & (NT_N - 1);
  if (mt >= NT_M) return;
  const int gm = mt * BM, gn = nt * BN;

  constexpr int ABYTES = (AMODE == 3) ? BM * BK * 4 : BM * BK * 2;
  __shared__ __align__(16) char AldsRaw[ABYTES];
  __shared__ __align__(16) unsigned short Blds[BN * BK];

  const int tid = threadIdx.x;
  const int wid = tid >> 6, lane = tid & 63;
  const int kg = lane >> 4, lr = lane & 15;
  const int sx = lr & 7;

  f32x4 acc[FM][FN] = {};

  const int nkt = Kpad / BK;
  for (int kt = 0; kt < nkt; ++kt) {
    const int k0 = kt * BK;
    // ---- stage A ----
    if constexpr (AMODE == 1) {
      const unsigned short* A = (const unsigned short*)Av;
      unsigned short* Alds = (unsigned short*)AldsRaw;
      #pragma unroll
      for (int it = 0; it < AIT1; ++it) {
        int q = it * TH + tid;
        int r = q >> 3, s = q & 7;
        int grow = gm + r; if (grow > M - 1) grow = M - 1;
        gl2lds16(A + (size_t)grow * K + k0 + ((s ^ (r & 7)) << 3), &Alds[q * 8]);
      }
    } else {  // AMODE 3: raw f32, 16 slots/row, swizzled source
      const float* A = (const float*)Av;
      float* Af = (float*)AldsRaw;
      if (k0 + BK <= K) {
        #pragma unroll
        for (int it = 0; it < AIT3; ++it) {
          int q = it * TH + tid;
          int r = q >> 4, s = q & 15;
          int grow = gm + r; if (grow > M - 1) grow = M - 1;
          gl2lds16(A + (size_t)grow * K + k0 + ((s ^ (r & 15)) << 2), &Af[q * 4]);
        }
      } else {  // tail (K%4==0): reg-staged, zero-masked
        #pragma unroll
        for (int it = 0; it < AIT3; ++it) {
          int q = it * TH + tid;
          int r = q >> 4, s = q & 15;
          int grow = gm + r; if (grow > M - 1) grow = M - 1;
          int kbase = k0 + ((s ^ (r & 15)) << 2);
          f32x4 v = {0.f, 0.f, 0.f, 0.f};
          if (kbase + 4 <= K) v = *(const f32x4*)(A + (size_t)grow * K + kbase);
          *(f32x4*)(&Af[q * 4]) = v;
        }
      }
    }
    // ---- stage B via gl2lds (linear dest, inverse-swizzled source) ----
    #pragma unroll
    for (int it = 0; it < BIT; ++it) {
      int q = it * TH + tid;
      int r = q >> 3, s = q & 7;
      gl2lds16(Bt + (size_t)(gn + r) * Kpad + k0 + ((s ^ (r & 7)) << 3), &Blds[q * 8]);
    }
    __syncthreads();
    // ---- fragments + MFMA (2 K-slices of 32) ----
    #pragma unroll
    for (int ks = 0; ks < 2; ++ks) {
      const int k8 = ks * 4 + kg;
      short8 af[FM];
      #pragma unroll
      for (int m = 0; m < FM; m++) {
        int r = m * 16 + lr;                 // r & 15 == lr
        if constexpr (AMODE == 1) {
          const unsigned short* Alds = (const unsigned short*)AldsRaw;
          af[m] = *(const short8*)(&Alds[(r * 8 + (k8 ^ sx)) * 8]);
        } else {
          const float* Af = (const float*)AldsRaw;
          int s0 = (2 * k8) ^ lr, s1 = (2 * k8 + 1) ^ lr;
          f32x4 lo = *(const f32x4*)(Af + r * 64 + s0 * 4);
          f32x4 hi = *(const f32x4*)(Af + r * 64 + s1 * 4);
          #pragma unroll
          for (int i = 0; i < 4; i++) {
            af[m][i]     = (short)f2bf_hw(lo[i]);
            af[m][i + 4] = (short)f2bf_hw(hi[i]);
          }
        }
      }
      #pragma unroll
      for (int n2 = 0; n2 < FN; n2++) {
        int cc = wid * WCOLS + n2 * 16 + lr;
        short8 bq = *(const short8*)(&Blds[(cc * 8 + (k8 ^ sx)) * 8]);
        #pragma unroll
        for (int m = 0; m < FM; m++)
          acc[m][n2] = __builtin_amdgcn_mfma_f32_16x16x32_bf16(af[m], bq, acc[m][n2], 0, 0, 0);
      }
    }
    __syncthreads();
  }
  // ---- epilogue: C/D layout col=lane&15, row=(lane>>4)*4+reg ----
  #pragma unroll
  for (int m = 0; m < FM; m++) {
    #pragma unroll
    for (int jj = 0; jj < 4; jj++) {
      int grow = gm + m * 16 + kg * 4 + jj;
      if (grow < M) {
        #pragma unroll
        for (int n2 = 0; n2 < FN; n2++) {
          int gcol = gn + wid * WCOLS + n2 * 16 + lr;
          float v = acc[m][n2][jj];
          if constexpr (ADD_BIAS) v += bias[gcol];
          if constexpr (DO_RELU) v = fmaxf(v, 0.f);
          C[(size_t)grow * N + gcol] = f2bf(v);
        }
      }
    }
  }
}

// ---------------- single-job GEMM (final layer), r8-proven config ----------------
template<int BM, int BN, int TH, int NT_N, int AMODE, bool ADD_BIAS, bool DO_RELU>
__global__ __launch_bounds__(TH, 2)
void gemm7(const void* __restrict__ Av, const unsigned short* __restrict__ Bt,
           const float* __restrict__ bias, unsigned short* __restrict__ C,
           int NT_M, int M, int N, int K, int Kpad) {
  constexpr int BK = 64;
  constexpr int WN = TH / 64;
  constexpr int WCOLS = BN / WN;
  constexpr int FM = BM / 16, FN = WCOLS / 16;
  constexpr int BIT  = (BN * 8) / TH;
  constexpr int AIT1 = (BM * 8) / TH;
  constexpr int LOGN = (NT_N == 2) ? 1 : 0;

  const int bid = blockIdx.x;
  const int xcd = bid & 7, j = bid >> 3;
  const int per = (NT_M + 7) >> 3;
  const int mt = xcd * per + (j >> LOGN);
  const int nt = j & (NT_N - 1);
  if (mt >= NT_M) return;
  const int gm = mt * BM, gn = nt * BN;

  __shared__ __align__(16) unsigned short Alds[BM * BK];
  __shared__ __align__(16) unsigned short Blds[BN * BK];

  const int tid = threadIdx.x;
  const int wid = tid >> 6, lane = tid & 63;
  const int kg = lane >> 4, lr = lane & 15;
  const int sx = lr & 7;

  f32x4 acc[FM][FN] = {};

  const int nkt = Kpad / BK;
  for (int kt = 0; kt < nkt; ++kt) {
    const int k0 = kt * BK;
    const unsigned short* A = (const unsigned short*)Av;
    #pragma unroll
    for (int it = 0; it < AIT1; ++it) {
      int q = it * TH + tid;
      int r = q >> 3, s = q & 7;
      int grow = gm + r; if (grow > M - 1) grow = M - 1;
      gl2lds16(A + (size_t)grow * K + k0 + ((s ^ (r & 7)) << 3), &Alds[q * 8]);
    }
    #pragma unroll
    for (int it = 0; it < BIT; ++it) {
      int q = it * TH + tid;
      int r = q >> 3, s = q & 7;
      gl2lds16(Bt + (size_t)(gn + r) * Kpad + k0 + ((s ^ (r & 7)) << 3), &Blds[q * 8]);
    }
    __syncthreads();
    #pragma unroll
    for (int ks = 0; ks < 2; ++ks) {
      const int k8 = ks * 4 + kg;
      short8 af[FM];
      #pragma unroll
      for (int m = 0; m < FM; m++) {
        int r = m * 16 + lr;
        af[m] = *(const short8*)(&Alds[(r * 8 + (k8 ^ sx)) * 8]);
      }
      #pragma unroll
      for (int n2 = 0; n2 < FN; n2++) {
        int cc = wid * WCOLS + n2 * 16 + lr;
        short8 bq = *(const short8*)(&Blds[(cc * 8 + (k8 ^ sx)) * 8]);
        #pragma unroll
        for (int m = 0; m < FM; m++)
          acc[m][n2] = __builtin_amdgcn_mfma_f32_16x16x32_bf16(af[m], bq, acc[m][n2], 0, 0, 0);
      }
    }
    __syncthreads();
  }
  #pragma unroll
  for (int m = 0; m < FM; m++) {
    #pragma unroll
    for (int jj = 0; jj < 4; jj++) {
      int grow = gm + m * 16 + kg * 4 + jj;
      if (grow < M) {
        #pragma unroll
        for (int n2 = 0; n2 < FN; n2++) {
          int gcol = gn + wid * WCOLS + n2 * 16 + lr;
          float v = acc[m][n2][jj];
          if constexpr (ADD_BIAS) v += bias[gcol];
          if constexpr (DO_RELU) v = fmaxf(v, 0.f);
          C[(size_t)grow * N + gcol] = f2bf(v);
        }
      }
    }
  }
}

// ---------------- per-graph GCN gather: 4-way unrolled edge loop ----------------
template<int LDH>
__device__ __forceinline__ f32x4 gcn_gather(const unsigned short* __restrict__ h,
                                            const int* __restrict__ rp,
                                            const int* __restrict__ cs,
                                            const float* __restrict__ cn,
                                            const float* __restrict__ dv,
                                            int node, int c4) {
  float d = dv[node];
  float sc = d * d;
  f32x4 a0, a1 = {0.f,0.f,0.f,0.f}, a2 = {0.f,0.f,0.f,0.f}, a3 = {0.f,0.f,0.f,0.f};
  {
    short4v v = *(const short4v*)(h + (size_t)node * LDH + c4);
    a0[0] = sc * bf2f((unsigned short)v[0]);
    a0[1] = sc * bf2f((unsigned short)v[1]);
    a0[2] = sc * bf2f((unsigned short)v[2]);
    a0[3] = sc * bf2f((unsigned short)v[3]);
  }
  int e = rp[node];
  const int e1 = rp[node + 1];
  for (; e + 4 <= e1; e += 4) {               // 4 independent gathers in flight
    int s0 = cs[e], s1 = cs[e+1], s2 = cs[e+2], s3 = cs[e+3];
    float n0 = cn[e], n1 = cn[e+1], n2 = cn[e+2], n3 = cn[e+3];
    short4v v0 = *(const short4v*)(h + (size_t)s0 * LDH + c4);
    short4v v1 = *(const short4v*)(h + (size_t)s1 * LDH + c4);
    short4v v2 = *(const short4v*)(h + (size_t)s2 * LDH + c4);
    short4v v3 = *(const short4v*)(h + (size_t)s3 * LDH + c4);
    #pragma unroll
    for (int i = 0; i < 4; i++) {
      a0[i] += n0 * bf2f((unsigned short)v0[i]);
      a1[i] += n1 * bf2f((unsigned short)v1[i]);
      a2[i] += n2 * bf2f((unsigned short)v2[i]);
      a3[i] += n3 * bf2f((unsigned short)v3[i]);
    }
  }
  for (; e < e1; ++e) {
    int s0 = cs[e]; float n0 = cn[e];
    short4v v0 = *(const short4v*)(h + (size_t)s0 * LDH + c4);
    #pragma unroll
    for (int i = 0; i < 4; i++) a0[i] += n0 * bf2f((unsigned short)v0[i]);
  }
  #pragma unroll
  for (int i = 0; i < 4; i++) a0[i] += a1[i] + a2[i] + a3[i];
  return a0;
}

// ---------------- fused dual-graph GCN scatter ----------------
// out = w * act(gcnA(hA)+bA) + (1-w) * act(gcnB(hB)+bB), act = relu or identity.
template<int F, int LDHA, int LDHB, bool DO_RELU, bool OUT_BF16>
__global__ __launch_bounds__(256)
void scatter_fused(const unsigned short* __restrict__ hA, const unsigned short* __restrict__ hB,
                   const int* __restrict__ rpA, const int* __restrict__ csA,
                   const float* __restrict__ cnA, const float* __restrict__ dvA,
                   const float* __restrict__ bA,
                   const int* __restrict__ rpB, const int* __restrict__ csB,
                   const float* __restrict__ cnB, const float* __restrict__ dvB,
                   const float* __restrict__ bB,
                   const float* __restrict__ wptr, void* __restrict__ outp, int n) {
  constexpr int TPN = F / 4;
  const int tid = threadIdx.x;
  const int node = blockIdx.x * (256 / TPN) + tid / TPN;
  const int c4 = (tid % TPN) * 4;
  if (node >= n) return;

  f32x4 accA = gcn_gather<LDHA>(hA, rpA, csA, cnA, dvA, node, c4);
  f32x4 accB = gcn_gather<LDHB>(hB, rpB, csB, cnB, dvB, node, c4);

  f32x4 bvA = *(const f32x4*)(bA + c4);
  f32x4 bvB = *(const f32x4*)(bB + c4);
  float w = *wptr;
  size_t idx = (size_t)node * F + c4;
  f32x4 r;
  #pragma unroll
  for (int i = 0; i < 4; i++) {
    float va = accA[i] + bvA[i];
    float vb = accB[i] + bvB[i];
    if constexpr (DO_RELU) { va = fmaxf(va, 0.f); vb = fmaxf(vb, 0.f); }
    r[i] = w * va + (1.f - w) * vb;
  }
  if constexpr (OUT_BF16) {
    short4v o;
    o[0] = (short)f2bf(r[0]); o[1] = (short)f2bf(r[1]);
    o[2] = (short)f2bf(r[2]); o[3] = (short)f2bf(r[3]);
    *(short4v*)((unsigned short*)outp + idx) = o;
  } else {
    *(f32x4*)((float*)outp + idx) = r;
  }
}

// ---------------- host ----------------
extern "C" void kernel_launch(void* const* d_in, const int* in_sizes, int n_in,
                              void* d_out, int out_size, void* d_ws, size_t ws_size,
                              hipStream_t stream) {
  const float* gene  = (const float*)d_in[0];
  const float* img   = (const float*)d_in[1];
  const int* ei_ge = (const int*)d_in[2];   // integers arrive as int32
  const int* ei_sp = (const int*)d_in[3];
  const float* W_fc1 = (const float*)d_in[4];  const float* b_fc1 = (const float*)d_in[5];
  const float* W_fc2 = (const float*)d_in[6];  const float* b_fc2 = (const float*)d_in[7];
  const float* W_g11 = (const float*)d_in[8];  const float* b_g11 = (const float*)d_in[9];
  const float* W_g12 = (const float*)d_in[10]; const float* b_g12 = (const float*)d_in[11];
  const float* W_g21 = (const float*)d_in[12]; const float* b_g21 = (const float*)d_in[13];
  const float* W_g22 = (const float*)d_in[14]; const float* b_g22 = (const float*)d_in[15];
  const float* w1p   = (const float*)d_in[16];
  const float* w2p   = (const float*)d_in[17];

  const int Nn = 50000;
  const int E_ge = in_sizes[2] / 2;
  const int E_sp = in_sizes[3] / 2;
  const int NT_M = CDIV(Nn, 64);             // 782 M-tiles of 64
  const int PER  = CDIV(NT_M, 8);            // 98
  const int G1   = 8 * PER;                  // 784 (NT_N=1), % 8 == 0
  const int G2   = 8 * PER * 2;              // 1568 (NT_N=2), % 8 == 0

  char* ws = (char*)d_ws;
  size_t off = 0;
  auto alloc = [&](size_t bytes) -> void* {
    void* p = ws + off;
    off += (bytes + 255) & ~(size_t)255;
    return p;
  };

  unsigned short* Wt1  = (unsigned short*)alloc((size_t)512 * 3008 * 2);
  unsigned short* Wt2  = (unsigned short*)alloc((size_t)512 * 1024 * 2);
  unsigned short* Wt11 = (unsigned short*)alloc((size_t)256 * 512 * 2);
  unsigned short* Wt12 = (unsigned short*)alloc((size_t)256 * 512 * 2);
  unsigned short* WtC  = (unsigned short*)alloc((size_t)128 * 256 * 2);  // [W_g21 | W_g22] rows
  int*   deg_sp  = (int*)alloc((size_t)Nn * 4);
  int*   deg_ge  = (int*)alloc((size_t)Nn * 4);
  float* dinv_sp = (float*)alloc((size_t)Nn * 4);
  float* dinv_ge = (float*)alloc((size_t)Nn * 4);
  int*   rp_sp   = (int*)alloc((size_t)(Nn + 1) * 4);
  int*   rp_ge   = (int*)alloc((size_t)(Nn + 1) * 4);
  int*   cur_sp  = (int*)alloc((size_t)Nn * 4);
  int*   cur_ge  = (int*)alloc((size_t)Nn * 4);
  int*   csrc_sp = (int*)alloc((size_t)E_sp * 4);
  float* cnrm_sp = (float*)alloc((size_t)E_sp * 4);
  int*   csrc_ge = (int*)alloc((size_t)E_ge * 4);
  float* cnrm_ge = (float*)alloc((size_t)E_ge * 4);
  unsigned short* xbuf1 = (unsigned short*)alloc((size_t)Nn * 512 * 2);  // x1 / Xc
  unsigned short* xbuf2 = (unsigned short*)alloc((size_t)Nn * 512 * 2);  // x2
  unsigned short* tmpA  = (unsigned short*)alloc((size_t)Nn * 256 * 2);  // g11 out; later tmp2
  unsigned short* tmpB  = (unsigned short*)alloc((size_t)Nn * 256 * 2);  // g12 out
  unsigned short* Xc    = xbuf1;
  unsigned short* tmp2  = tmpA;
  (void)ws_size; (void)n_in; (void)out_size;

  // 1. weight transposes (bf16, K zero-padded)
  transpose_w<<<dim3(94, 16), 256, 0, stream>>>(W_fc1, Wt1, 3000, 512, 3008);
  transpose_w<<<dim3(32, 16), 256, 0, stream>>>(W_fc2, Wt2, 1024, 512, 1024);
  transpose_w<<<dim3(16, 8),  256, 0, stream>>>(W_g11, Wt11, 512, 256, 512);
  transpose_w<<<dim3(16, 8),  256, 0, stream>>>(W_g12, Wt12, 512, 256, 512);
  transpose_w<<<dim3(8, 2),   256, 0, stream>>>(W_g21, WtC, 256, 64, 256);
  transpose_w<<<dim3(8, 2),   256, 0, stream>>>(W_g22, WtC + (size_t)64 * 256, 256, 64, 256);

  // 2. graph prep (consolidated)
  prep_init<<<CDIV(Nn, 256), 256, 0, stream>>>(deg_sp, deg_ge, cur_sp, cur_ge, Nn);
  deg_hist_both<<<CDIV(E_sp + E_ge, 256), 256, 0, stream>>>(
      ei_sp, E_sp, deg_sp, ei_ge, E_ge, deg_ge, Nn);
  dinv_both<<<CDIV(Nn, 256), 256, 0, stream>>>(deg_sp, dinv_sp, deg_ge, dinv_ge, Nn);
  scan_rowptr_dual<<<2, 1024, 0, stream>>>(deg_sp, rp_sp, deg_ge, rp_ge, Nn);
  csr_fill_both<<<CDIV(E_sp + E_ge, 256), 256, 0, stream>>>(
      ei_sp, E_sp, rp_sp, cur_sp, dinv_sp, csrc_sp, cnrm_sp,
      ei_ge, E_ge, rp_ge, cur_ge, dinv_ge, csrc_ge, cnrm_ge, Nn);

  // 3. FC1 + FC2 in one launch, GROUP-INTERLEAVED (XCD digit preserved):
  //    x1 = relu(gene@W1+b) ; x2 = relu(img@W2+b)
  gemm_pair<64, 256, 256, 2, 3, true, true><<<2 * G2, 256, 0, stream>>>(
      gene, Wt1, b_fc1, xbuf1, 3000, 3008,
      img,  Wt2, b_fc2, xbuf2, 1024, 1024,
      NT_M, Nn, 512);
  // 4. mids in one launch: tmpA = x1 @ W_g11 ; tmpB = x2 @ W_g12
  gemm_pair<64, 256, 256, 1, 1, false, false><<<2 * G1, 256, 0, stream>>>(
      xbuf1, Wt11, nullptr, tmpA, 512, 512,
      xbuf2, Wt12, nullptr, tmpB, 512, 512,
      NT_M, Nn, 256);
  // 5. Xc = bf16( w1*relu(gcn_sp(tmpA)+b_g11) + (1-w1)*relu(gcn_ge(tmpB)+b_g12) )
  scatter_fused<256, 256, 256, true, true><<<Nn / 4, 256, 0, stream>>>(
      tmpA, tmpB, rp_sp, csrc_sp, cnrm_sp, dinv_sp, b_g11,
      rp_ge, csrc_ge, cnrm_ge, dinv_ge, b_g12, w1p, Xc, Nn);
  // 6. tmp2 = Xc @ [W_g21 | W_g22]  (N=128, one pass; tmp2 aliases tmpA)
  gemm7<64, 128, 256, 1, 1, false, false><<<G1, 256, 0, stream>>>(
      Xc, WtC, nullptr, tmp2, NT_M, Nn, 128, 256, 256);
  // 7. d_out = w2*(gcn_sp(tmp2[:,0:64])+b_g21) + (1-w2)*(gcn_ge(tmp2[:,64:128])+b_g22)
  scatter_fused<64, 128, 128, false, false><<<Nn / 16, 256, 0, stream>>>(
      tmp2, tmp2 + 64, rp_sp, csrc_sp, cnrm_sp, dinv_sp, b_g21,
      rp_ge, csrc_ge, cnrm_ge, dinv_ge, b_g22, w2p, d_out, Nn);
}

// Round 17
// 737.250 us; speedup vs baseline: 1.2499x; 1.2499x over previous
//
#include <hip/hip_runtime.h>
#include <hip/hip_bf16.h>
#include <stdint.h>

typedef __attribute__((ext_vector_type(4))) float f32x4;
typedef __attribute__((ext_vector_type(8))) short short8;
typedef __attribute__((ext_vector_type(4))) short short4v;

#define CDIV(a, b) (((a) + (b) - 1) / (b))

__device__ __forceinline__ unsigned short f2bf(float x) {
  union { float f; unsigned int u; } c; c.f = x;
  unsigned int r = c.u + 0x7FFFu + ((c.u >> 16) & 1u);   // round-to-nearest-even
  return (unsigned short)(r >> 16);
}
__device__ __forceinline__ unsigned short f2bf_hw(float x) {
  __hip_bfloat16 h = __float2bfloat16(x);                // pairs fuse into v_cvt_pk_bf16_f32
  unsigned short u; __builtin_memcpy(&u, &h, 2); return u;
}
__device__ __forceinline__ float bf2f(unsigned short b) {
  union { unsigned int u; float f; } c; c.u = (unsigned int)b << 16; return c.f;
}

// async global->LDS, 16B per lane; LDS dest must be wave-uniform base + lane*16 (linear)
__device__ __forceinline__ void gl2lds16(const void* g, void* lds) {
  __builtin_amdgcn_global_load_lds(
      reinterpret_cast<const __attribute__((address_space(1))) unsigned int*>(
          reinterpret_cast<uintptr_t>(g)),
      reinterpret_cast<__attribute__((address_space(3))) unsigned int*>(
          reinterpret_cast<uintptr_t>(lds)),
      16, 0, 0);
}

// ---------------- weight transpose: W[K][N] f32 -> Wt[N][Kpad] bf16, zero-padded ----------------
__global__ void transpose_w(const float* __restrict__ W, unsigned short* __restrict__ Wt,
                            int K, int N, int Kpad) {
  __shared__ float tile[32][33];
  int kb = blockIdx.x * 32, nb = blockIdx.y * 32;
  int tx = threadIdx.x & 31, ty = threadIdx.x >> 5;  // 256 threads = 32x8
  for (int r = ty; r < 32; r += 8) {
    int k = kb + r, n = nb + tx;
    tile[r][tx] = (k < K && n < N) ? W[(size_t)k * N + n] : 0.f;
  }
  __syncthreads();
  for (int r = ty; r < 32; r += 8) {
    int n = nb + r, k = kb + tx;
    if (n < N && k < Kpad) Wt[(size_t)n * Kpad + k] = f2bf(tile[tx][r]);
  }
}

// ---------------- graph prep (consolidated: both graphs per launch) ----------------
__global__ void prep_init(int* __restrict__ dA, int* __restrict__ dB,
                          int* __restrict__ cA, int* __restrict__ cB, int n) {
  int i = blockIdx.x * blockDim.x + threadIdx.x;
  if (i < n) { dA[i] = 1; dB[i] = 1; cA[i] = 0; cB[i] = 0; }   // deg=1 (self-loop), cursor=0
}

__global__ void deg_hist_both(const int* __restrict__ eiA, int EA, int* __restrict__ degA,
                              const int* __restrict__ eiB, int EB, int* __restrict__ degB, int n) {
  int e = blockIdx.x * blockDim.x + threadIdx.x;
  if (e < EA) {
    unsigned int d = (unsigned int)eiA[(size_t)EA + e];
    if (d < (unsigned int)n) atomicAdd(&degA[d], 1);
  } else if (e < EA + EB) {
    int e2 = e - EA;
    unsigned int d = (unsigned int)eiB[(size_t)EB + e2];
    if (d < (unsigned int)n) atomicAdd(&degB[d], 1);
  }
}

__global__ void dinv_both(const int* __restrict__ dA, float* __restrict__ vA,
                          const int* __restrict__ dB, float* __restrict__ vB, int n) {
  int i = blockIdx.x * blockDim.x + threadIdx.x;
  if (i < n) { vA[i] = rsqrtf((float)dA[i]); vB[i] = rsqrtf((float)dB[i]); }
}

// exclusive scan of (deg-1) -> row_ptr[0..n]; blockIdx.x selects graph
__global__ void scan_rowptr_dual(const int* __restrict__ degA, int* __restrict__ rpA,
                                 const int* __restrict__ degB, int* __restrict__ rpB, int n) {
  const int* deg = (blockIdx.x == 0) ? degA : degB;
  int* rp = (blockIdx.x == 0) ? rpA : rpB;
  __shared__ int wsum[16];
  __shared__ int carry_s;
  const int tid = threadIdx.x, lane = tid & 63, w = tid >> 6;
  if (tid == 0) carry_s = 0;
  __syncthreads();
  for (int base = 0; base < n; base += 1024) {
    int i = base + tid;
    int d = (i < n) ? (deg[i] - 1) : 0;
    int v = d;
    #pragma unroll
    for (int off = 1; off < 64; off <<= 1) {
      int t = __shfl_up(v, off, 64);
      if (lane >= off) v += t;
    }
    if (lane == 63) wsum[w] = v;
    __syncthreads();
    int carry = carry_s;
    if (w == 0) {
      int s = (lane < 16) ? wsum[lane] : 0;
      #pragma unroll
      for (int off = 1; off < 16; off <<= 1) {
        int t = __shfl_up(s, off, 64);
        if (lane >= off) s += t;
      }
      if (lane < 16) wsum[lane] = s;
    }
    __syncthreads();
    int woff = (w > 0) ? wsum[w - 1] : 0;
    if (i < n) rp[i] = carry + woff + v - d;
    if (tid == 0) carry_s = carry + wsum[15];
    __syncthreads();
  }
  if (threadIdx.x == 0) rp[n] = carry_s;
}

__global__ void csr_fill_both(const int* __restrict__ eiA, int EA, const int* __restrict__ rpA,
                              int* __restrict__ curA, const float* __restrict__ dvA,
                              int* __restrict__ csA, float* __restrict__ cnA,
                              const int* __restrict__ eiB, int EB, const int* __restrict__ rpB,
                              int* __restrict__ curB, const float* __restrict__ dvB,
                              int* __restrict__ csB, float* __restrict__ cnB, int n) {
  int e = blockIdx.x * blockDim.x + threadIdx.x;
  if (e < EA) {
    unsigned int s = (unsigned int)eiA[e];
    unsigned int d = (unsigned int)eiA[(size_t)EA + e];
    if (s < (unsigned int)n && d < (unsigned int)n) {
      int pos = rpA[d] + atomicAdd(&curA[d], 1);
      csA[pos] = (int)s;
      cnA[pos] = dvA[s] * dvA[d];
    }
  } else if (e < EA + EB) {
    int e2 = e - EA;
    unsigned int s = (unsigned int)eiB[e2];
    unsigned int d = (unsigned int)eiB[(size_t)EB + e2];
    if (s < (unsigned int)n && d < (unsigned int)n) {
      int pos = rpB[d] + atomicAdd(&curB[d], 1);
      csB[pos] = (int)s;
      cnB[pos] = dvB[s] * dvB[d];
    }
  }
}

// ---------------- gemm_pair: TWO independent GEMMs, CONCATENATED block ranges ----------------
// Blocks [0,split) = job0, [split,..) = job1 (split % 8 == 0 so bid%8 == HW XCD is
// preserved for both jobs -> XCD-grouped locality intact; overlap at the job boundary
// gives mixed-phase blocks without L2 working-set collision during the bulk phase).
// Body = r8-proven gemm7. AMODE 1: A bf16 via gl2lds. AMODE 3: A f32 RAW via gl2lds,
// bf16 cvt at fragment read; K-tail reg-staged zero-masked (K%4==0).
template<int BM, int BN, int TH, int NT_N, int AMODE, bool ADD_BIAS, bool DO_RELU>
__global__ __launch_bounds__(TH, 2)
void gemm_pair(const void* __restrict__ A0, const unsigned short* __restrict__ Bt0,
               const float* __restrict__ b0, unsigned short* __restrict__ C0, int K0, int Kp0,
               const void* __restrict__ A1, const unsigned short* __restrict__ Bt1,
               const float* __restrict__ b1, unsigned short* __restrict__ C1, int K1, int Kp1,
               int split, int NT_M, int M, int N) {
  constexpr int BK = 64;
  constexpr int WN = TH / 64;
  constexpr int WCOLS = BN / WN;
  constexpr int FM = BM / 16, FN = WCOLS / 16;
  constexpr int BIT  = (BN * 8) / TH;
  constexpr int AIT1 = (BM * 8) / TH;
  constexpr int AIT3 = (BM * 16) / TH;
  constexpr int LOGN = (NT_N == 4) ? 2 : (NT_N == 2 ? 1 : 0);

  const int bid0 = blockIdx.x;
  const bool j1 = (bid0 >= split);
  const int bid = j1 ? (bid0 - split) : bid0;
  const void* Av = j1 ? A1 : A0;
  const unsigned short* Bt = j1 ? Bt1 : Bt0;
  const float* bias = j1 ? b1 : b0;
  unsigned short* C = j1 ? C1 : C0;
  const int K = j1 ? K1 : K0;
  const int Kpad = j1 ? Kp1 : Kp0;

  const int xcd = bid & 7, j = bid >> 3;
  const int per = (NT_M + 7) >> 3;
  const int mt = xcd * per + (j >> LOGN);
  const int nt = j & (NT_N - 1);
  if (mt >= NT_M) return;
  const int gm = mt * BM, gn = nt * BN;

  constexpr int ABYTES = (AMODE == 3) ? BM * BK * 4 : BM * BK * 2;
  __shared__ __align__(16) char AldsRaw[ABYTES];
  __shared__ __align__(16) unsigned short Blds[BN * BK];

  const int tid = threadIdx.x;
  const int wid = tid >> 6, lane = tid & 63;
  const int kg = lane >> 4, lr = lane & 15;
  const int sx = lr & 7;

  f32x4 acc[FM][FN] = {};

  const int nkt = Kpad / BK;
  for (int kt = 0; kt < nkt; ++kt) {
    const int k0 = kt * BK;
    // ---- stage A ----
    if constexpr (AMODE == 1) {
      const unsigned short* A = (const unsigned short*)Av;
      unsigned short* Alds = (unsigned short*)AldsRaw;
      #pragma unroll
      for (int it = 0; it < AIT1; ++it) {
        int q = it * TH + tid;
        int r = q >> 3, s = q & 7;
        int grow = gm + r; if (grow > M - 1) grow = M - 1;
        gl2lds16(A + (size_t)grow * K + k0 + ((s ^ (r & 7)) << 3), &Alds[q * 8]);
      }
    } else {  // AMODE 3: raw f32, 16 slots/row, swizzled source
      const float* A = (const float*)Av;
      float* Af = (float*)AldsRaw;
      if (k0 + BK <= K) {
        #pragma unroll
        for (int it = 0; it < AIT3; ++it) {
          int q = it * TH + tid;
          int r = q >> 4, s = q & 15;
          int grow = gm + r; if (grow > M - 1) grow = M - 1;
          gl2lds16(A + (size_t)grow * K + k0 + ((s ^ (r & 15)) << 2), &Af[q * 4]);
        }
      } else {  // tail (K%4==0): reg-staged, zero-masked
        #pragma unroll
        for (int it = 0; it < AIT3; ++it) {
          int q = it * TH + tid;
          int r = q >> 4, s = q & 15;
          int grow = gm + r; if (grow > M - 1) grow = M - 1;
          int kbase = k0 + ((s ^ (r & 15)) << 2);
          f32x4 v = {0.f, 0.f, 0.f, 0.f};
          if (kbase + 4 <= K) v = *(const f32x4*)(A + (size_t)grow * K + kbase);
          *(f32x4*)(&Af[q * 4]) = v;
        }
      }
    }
    // ---- stage B via gl2lds (linear dest, inverse-swizzled source) ----
    #pragma unroll
    for (int it = 0; it < BIT; ++it) {
      int q = it * TH + tid;
      int r = q >> 3, s = q & 7;
      gl2lds16(Bt + (size_t)(gn + r) * Kpad + k0 + ((s ^ (r & 7)) << 3), &Blds[q * 8]);
    }
    __syncthreads();
    // ---- fragments + MFMA (2 K-slices of 32) ----
    #pragma unroll
    for (int ks = 0; ks < 2; ++ks) {
      const int k8 = ks * 4 + kg;
      short8 af[FM];
      #pragma unroll
      for (int m = 0; m < FM; m++) {
        int r = m * 16 + lr;                 // r & 15 == lr
        if constexpr (AMODE == 1) {
          const unsigned short* Alds = (const unsigned short*)AldsRaw;
          af[m] = *(const short8*)(&Alds[(r * 8 + (k8 ^ sx)) * 8]);
        } else {
          const float* Af = (const float*)AldsRaw;
          int s0 = (2 * k8) ^ lr, s1 = (2 * k8 + 1) ^ lr;
          f32x4 lo = *(const f32x4*)(Af + r * 64 + s0 * 4);
          f32x4 hi = *(const f32x4*)(Af + r * 64 + s1 * 4);
          #pragma unroll
          for (int i = 0; i < 4; i++) {
            af[m][i]     = (short)f2bf_hw(lo[i]);
            af[m][i + 4] = (short)f2bf_hw(hi[i]);
          }
        }
      }
      #pragma unroll
      for (int n2 = 0; n2 < FN; n2++) {
        int cc = wid * WCOLS + n2 * 16 + lr;
        short8 bq = *(const short8*)(&Blds[(cc * 8 + (k8 ^ sx)) * 8]);
        #pragma unroll
        for (int m = 0; m < FM; m++)
          acc[m][n2] = __builtin_amdgcn_mfma_f32_16x16x32_bf16(af[m], bq, acc[m][n2], 0, 0, 0);
      }
    }
    __syncthreads();
  }
  // ---- epilogue: C/D layout col=lane&15, row=(lane>>4)*4+reg ----
  #pragma unroll
  for (int m = 0; m < FM; m++) {
    #pragma unroll
    for (int jj = 0; jj < 4; jj++) {
      int grow = gm + m * 16 + kg * 4 + jj;
      if (grow < M) {
        #pragma unroll
        for (int n2 = 0; n2 < FN; n2++) {
          int gcol = gn + wid * WCOLS + n2 * 16 + lr;
          float v = acc[m][n2][jj];
          if constexpr (ADD_BIAS) v += bias[gcol];
          if constexpr (DO_RELU) v = fmaxf(v, 0.f);
          C[(size_t)grow * N + gcol] = f2bf(v);
        }
      }
    }
  }
}

// ---------------- single-job GEMM (final layer), r8-proven config ----------------
template<int BM, int BN, int TH, int NT_N, int AMODE, bool ADD_BIAS, bool DO_RELU>
__global__ __launch_bounds__(TH, 2)
void gemm7(const void* __restrict__ Av, const unsigned short* __restrict__ Bt,
           const float* __restrict__ bias, unsigned short* __restrict__ C,
           int NT_M, int M, int N, int K, int Kpad) {
  constexpr int BK = 64;
  constexpr int WN = TH / 64;
  constexpr int WCOLS = BN / WN;
  constexpr int FM = BM / 16, FN = WCOLS / 16;
  constexpr int BIT  = (BN * 8) / TH;
  constexpr int AIT1 = (BM * 8) / TH;
  constexpr int LOGN = (NT_N == 2) ? 1 : 0;

  const int bid = blockIdx.x;
  const int xcd = bid & 7, j = bid >> 3;
  const int per = (NT_M + 7) >> 3;
  const int mt = xcd * per + (j >> LOGN);
  const int nt = j & (NT_N - 1);
  if (mt >= NT_M) return;
  const int gm = mt * BM, gn = nt * BN;

  __shared__ __align__(16) unsigned short Alds[BM * BK];
  __shared__ __align__(16) unsigned short Blds[BN * BK];

  const int tid = threadIdx.x;
  const int wid = tid >> 6, lane = tid & 63;
  const int kg = lane >> 4, lr = lane & 15;
  const int sx = lr & 7;

  f32x4 acc[FM][FN] = {};

  const int nkt = Kpad / BK;
  for (int kt = 0; kt < nkt; ++kt) {
    const int k0 = kt * BK;
    const unsigned short* A = (const unsigned short*)Av;
    #pragma unroll
    for (int it = 0; it < AIT1; ++it) {
      int q = it * TH + tid;
      int r = q >> 3, s = q & 7;
      int grow = gm + r; if (grow > M - 1) grow = M - 1;
      gl2lds16(A + (size_t)grow * K + k0 + ((s ^ (r & 7)) << 3), &Alds[q * 8]);
    }
    #pragma unroll
    for (int it = 0; it < BIT; ++it) {
      int q = it * TH + tid;
      int r = q >> 3, s = q & 7;
      gl2lds16(Bt + (size_t)(gn + r) * Kpad + k0 + ((s ^ (r & 7)) << 3), &Blds[q * 8]);
    }
    __syncthreads();
    #pragma unroll
    for (int ks = 0; ks < 2; ++ks) {
      const int k8 = ks * 4 + kg;
      short8 af[FM];
      #pragma unroll
      for (int m = 0; m < FM; m++) {
        int r = m * 16 + lr;
        af[m] = *(const short8*)(&Alds[(r * 8 + (k8 ^ sx)) * 8]);
      }
      #pragma unroll
      for (int n2 = 0; n2 < FN; n2++) {
        int cc = wid * WCOLS + n2 * 16 + lr;
        short8 bq = *(const short8*)(&Blds[(cc * 8 + (k8 ^ sx)) * 8]);
        #pragma unroll
        for (int m = 0; m < FM; m++)
          acc[m][n2] = __builtin_amdgcn_mfma_f32_16x16x32_bf16(af[m], bq, acc[m][n2], 0, 0, 0);
      }
    }
    __syncthreads();
  }
  #pragma unroll
  for (int m = 0; m < FM; m++) {
    #pragma unroll
    for (int jj = 0; jj < 4; jj++) {
      int grow = gm + m * 16 + kg * 4 + jj;
      if (grow < M) {
        #pragma unroll
        for (int n2 = 0; n2 < FN; n2++) {
          int gcol = gn + wid * WCOLS + n2 * 16 + lr;
          float v = acc[m][n2][jj];
          if constexpr (ADD_BIAS) v += bias[gcol];
          if constexpr (DO_RELU) v = fmaxf(v, 0.f);
          C[(size_t)grow * N + gcol] = f2bf(v);
        }
      }
    }
  }
}

// ---------------- per-graph GCN gather: 4-way unrolled edge loop ----------------
template<int LDH>
__device__ __forceinline__ f32x4 gcn_gather(const unsigned short* __restrict__ h,
                                            const int* __restrict__ rp,
                                            const int* __restrict__ cs,
                                            const float* __restrict__ cn,
                                            const float* __restrict__ dv,
                                            int node, int c4) {
  float d = dv[node];
  float sc = d * d;
  f32x4 a0, a1 = {0.f,0.f,0.f,0.f}, a2 = {0.f,0.f,0.f,0.f}, a3 = {0.f,0.f,0.f,0.f};
  {
    short4v v = *(const short4v*)(h + (size_t)node * LDH + c4);
    a0[0] = sc * bf2f((unsigned short)v[0]);
    a0[1] = sc * bf2f((unsigned short)v[1]);
    a0[2] = sc * bf2f((unsigned short)v[2]);
    a0[3] = sc * bf2f((unsigned short)v[3]);
  }
  int e = rp[node];
  const int e1 = rp[node + 1];
  for (; e + 4 <= e1; e += 4) {               // 4 independent gathers in flight
    int s0 = cs[e], s1 = cs[e+1], s2 = cs[e+2], s3 = cs[e+3];
    float n0 = cn[e], n1 = cn[e+1], n2 = cn[e+2], n3 = cn[e+3];
    short4v v0 = *(const short4v*)(h + (size_t)s0 * LDH + c4);
    short4v v1 = *(const short4v*)(h + (size_t)s1 * LDH + c4);
    short4v v2 = *(const short4v*)(h + (size_t)s2 * LDH + c4);
    short4v v3 = *(const short4v*)(h + (size_t)s3 * LDH + c4);
    #pragma unroll
    for (int i = 0; i < 4; i++) {
      a0[i] += n0 * bf2f((unsigned short)v0[i]);
      a1[i] += n1 * bf2f((unsigned short)v1[i]);
      a2[i] += n2 * bf2f((unsigned short)v2[i]);
      a3[i] += n3 * bf2f((unsigned short)v3[i]);
    }
  }
  for (; e < e1; ++e) {
    int s0 = cs[e]; float n0 = cn[e];
    short4v v0 = *(const short4v*)(h + (size_t)s0 * LDH + c4);
    #pragma unroll
    for (int i = 0; i < 4; i++) a0[i] += n0 * bf2f((unsigned short)v0[i]);
  }
  #pragma unroll
  for (int i = 0; i < 4; i++) a0[i] += a1[i] + a2[i] + a3[i];
  return a0;
}

// ---------------- fused dual-graph GCN scatter ----------------
// out = w * act(gcnA(hA)+bA) + (1-w) * act(gcnB(hB)+bB), act = relu or identity.
template<int F, int LDHA, int LDHB, bool DO_RELU, bool OUT_BF16>
__global__ __launch_bounds__(256)
void scatter_fused(const unsigned short* __restrict__ hA, const unsigned short* __restrict__ hB,
                   const int* __restrict__ rpA, const int* __restrict__ csA,
                   const float* __restrict__ cnA, const float* __restrict__ dvA,
                   const float* __restrict__ bA,
                   const int* __restrict__ rpB, const int* __restrict__ csB,
                   const float* __restrict__ cnB, const float* __restrict__ dvB,
                   const float* __restrict__ bB,
                   const float* __restrict__ wptr, void* __restrict__ outp, int n) {
  constexpr int TPN = F / 4;
  const int tid = threadIdx.x;
  const int node = blockIdx.x * (256 / TPN) + tid / TPN;
  const int c4 = (tid % TPN) * 4;
  if (node >= n) return;

  f32x4 accA = gcn_gather<LDHA>(hA, rpA, csA, cnA, dvA, node, c4);
  f32x4 accB = gcn_gather<LDHB>(hB, rpB, csB, cnB, dvB, node, c4);

  f32x4 bvA = *(const f32x4*)(bA + c4);
  f32x4 bvB = *(const f32x4*)(bB + c4);
  float w = *wptr;
  size_t idx = (size_t)node * F + c4;
  f32x4 r;
  #pragma unroll
  for (int i = 0; i < 4; i++) {
    float va = accA[i] + bvA[i];
    float vb = accB[i] + bvB[i];
    if constexpr (DO_RELU) { va = fmaxf(va, 0.f); vb = fmaxf(vb, 0.f); }
    r[i] = w * va + (1.f - w) * vb;
  }
  if constexpr (OUT_BF16) {
    short4v o;
    o[0] = (short)f2bf(r[0]); o[1] = (short)f2bf(r[1]);
    o[2] = (short)f2bf(r[2]); o[3] = (short)f2bf(r[3]);
    *(short4v*)((unsigned short*)outp + idx) = o;
  } else {
    *(f32x4*)((float*)outp + idx) = r;
  }
}

// ---------------- host ----------------
extern "C" void kernel_launch(void* const* d_in, const int* in_sizes, int n_in,
                              void* d_out, int out_size, void* d_ws, size_t ws_size,
                              hipStream_t stream) {
  const float* gene  = (const float*)d_in[0];
  const float* img   = (const float*)d_in[1];
  const int* ei_ge = (const int*)d_in[2];   // integers arrive as int32
  const int* ei_sp = (const int*)d_in[3];
  const float* W_fc1 = (const float*)d_in[4];  const float* b_fc1 = (const float*)d_in[5];
  const float* W_fc2 = (const float*)d_in[6];  const float* b_fc2 = (const float*)d_in[7];
  const float* W_g11 = (const float*)d_in[8];  const float* b_g11 = (const float*)d_in[9];
  const float* W_g12 = (const float*)d_in[10]; const float* b_g12 = (const float*)d_in[11];
  const float* W_g21 = (const float*)d_in[12]; const float* b_g21 = (const float*)d_in[13];
  const float* W_g22 = (const float*)d_in[14]; const float* b_g22 = (const float*)d_in[15];
  const float* w1p   = (const float*)d_in[16];
  const float* w2p   = (const float*)d_in[17];

  const int Nn = 50000;
  const int E_ge = in_sizes[2] / 2;
  const int E_sp = in_sizes[3] / 2;
  const int NT_M = CDIV(Nn, 64);             // 782 M-tiles of 64
  const int PER  = CDIV(NT_M, 8);            // 98
  const int G1   = 8 * PER;                  // 784 (NT_N=1), % 8 == 0
  const int G2   = 8 * PER * 2;              // 1568 (NT_N=2), % 8 == 0

  char* ws = (char*)d_ws;
  size_t off = 0;
  auto alloc = [&](size_t bytes) -> void* {
    void* p = ws + off;
    off += (bytes + 255) & ~(size_t)255;
    return p;
  };

  unsigned short* Wt1  = (unsigned short*)alloc((size_t)512 * 3008 * 2);
  unsigned short* Wt2  = (unsigned short*)alloc((size_t)512 * 1024 * 2);
  unsigned short* Wt11 = (unsigned short*)alloc((size_t)256 * 512 * 2);
  unsigned short* Wt12 = (unsigned short*)alloc((size_t)256 * 512 * 2);
  unsigned short* WtC  = (unsigned short*)alloc((size_t)128 * 256 * 2);  // [W_g21 | W_g22] rows
  int*   deg_sp  = (int*)alloc((size_t)Nn * 4);
  int*   deg_ge  = (int*)alloc((size_t)Nn * 4);
  float* dinv_sp = (float*)alloc((size_t)Nn * 4);
  float* dinv_ge = (float*)alloc((size_t)Nn * 4);
  int*   rp_sp   = (int*)alloc((size_t)(Nn + 1) * 4);
  int*   rp_ge   = (int*)alloc((size_t)(Nn + 1) * 4);
  int*   cur_sp  = (int*)alloc((size_t)Nn * 4);
  int*   cur_ge  = (int*)alloc((size_t)Nn * 4);
  int*   csrc_sp = (int*)alloc((size_t)E_sp * 4);
  float* cnrm_sp = (float*)alloc((size_t)E_sp * 4);
  int*   csrc_ge = (int*)alloc((size_t)E_ge * 4);
  float* cnrm_ge = (float*)alloc((size_t)E_ge * 4);
  unsigned short* xbuf1 = (unsigned short*)alloc((size_t)Nn * 512 * 2);  // x1 / Xc
  unsigned short* xbuf2 = (unsigned short*)alloc((size_t)Nn * 512 * 2);  // x2
  unsigned short* tmpA  = (unsigned short*)alloc((size_t)Nn * 256 * 2);  // g11 out; later tmp2
  unsigned short* tmpB  = (unsigned short*)alloc((size_t)Nn * 256 * 2);  // g12 out
  unsigned short* Xc    = xbuf1;
  unsigned short* tmp2  = tmpA;
  (void)ws_size; (void)n_in; (void)out_size;

  // 1. weight transposes (bf16, K zero-padded)
  transpose_w<<<dim3(94, 16), 256, 0, stream>>>(W_fc1, Wt1, 3000, 512, 3008);
  transpose_w<<<dim3(32, 16), 256, 0, stream>>>(W_fc2, Wt2, 1024, 512, 1024);
  transpose_w<<<dim3(16, 8),  256, 0, stream>>>(W_g11, Wt11, 512, 256, 512);
  transpose_w<<<dim3(16, 8),  256, 0, stream>>>(W_g12, Wt12, 512, 256, 512);
  transpose_w<<<dim3(8, 2),   256, 0, stream>>>(W_g21, WtC, 256, 64, 256);
  transpose_w<<<dim3(8, 2),   256, 0, stream>>>(W_g22, WtC + (size_t)64 * 256, 256, 64, 256);

  // 2. graph prep (consolidated)
  prep_init<<<CDIV(Nn, 256), 256, 0, stream>>>(deg_sp, deg_ge, cur_sp, cur_ge, Nn);
  deg_hist_both<<<CDIV(E_sp + E_ge, 256), 256, 0, stream>>>(
      ei_sp, E_sp, deg_sp, ei_ge, E_ge, deg_ge, Nn);
  dinv_both<<<CDIV(Nn, 256), 256, 0, stream>>>(deg_sp, dinv_sp, deg_ge, dinv_ge, Nn);
  scan_rowptr_dual<<<2, 1024, 0, stream>>>(deg_sp, rp_sp, deg_ge, rp_ge, Nn);
  csr_fill_both<<<CDIV(E_sp + E_ge, 256), 256, 0, stream>>>(
      ei_sp, E_sp, rp_sp, cur_sp, dinv_sp, csrc_sp, cnrm_sp,
      ei_ge, E_ge, rp_ge, cur_ge, dinv_ge, csrc_ge, cnrm_ge, Nn);

  // 3. FC1 + FC2 in one launch, CONCATENATED ranges (XCD mapping preserved):
  //    x1 = relu(gene@W1+b) ; x2 = relu(img@W2+b)
  gemm_pair<64, 256, 256, 2, 3, true, true><<<2 * G2, 256, 0, stream>>>(
      gene, Wt1, b_fc1, xbuf1, 3000, 3008,
      img,  Wt2, b_fc2, xbuf2, 1024, 1024,
      G2, NT_M, Nn, 512);
  // 4. mids in one launch: tmpA = x1 @ W_g11 ; tmpB = x2 @ W_g12
  gemm_pair<64, 256, 256, 1, 1, false, false><<<2 * G1, 256, 0, stream>>>(
      xbuf1, Wt11, nullptr, tmpA, 512, 512,
      xbuf2, Wt12, nullptr, tmpB, 512, 512,
      G1, NT_M, Nn, 256);
  // 5. Xc = bf16( w1*relu(gcn_sp(tmpA)+b_g11) + (1-w1)*relu(gcn_ge(tmpB)+b_g12) )
  scatter_fused<256, 256, 256, true, true><<<Nn / 4, 256, 0, stream>>>(
      tmpA, tmpB, rp_sp, csrc_sp, cnrm_sp, dinv_sp, b_g11,
      rp_ge, csrc_ge, cnrm_ge, dinv_ge, b_g12, w1p, Xc, Nn);
  // 6. tmp2 = Xc @ [W_g21 | W_g22]  (N=128, one pass; tmp2 aliases tmpA)
  gemm7<64, 128, 256, 1, 1, false, false><<<G1, 256, 0, stream>>>(
      Xc, WtC, nullptr, tmp2, NT_M, Nn, 128, 256, 256);
  // 7. d_out = w2*(gcn_sp(tmp2[:,0:64])+b_g21) + (1-w2)*(gcn_ge(tmp2[:,64:128])+b_g22)
  scatter_fused<64, 128, 128, false, false><<<Nn / 16, 256, 0, stream>>>(
      tmp2, tmp2 + 64, rp_sp, csrc_sp, cnrm_sp, dinv_sp, b_g21,
      rp_ge, csrc_ge, cnrm_ge, dinv_ge, b_g22, w2p, d_out, Nn);
}

// Round 18
// 674.082 us; speedup vs baseline: 1.3670x; 1.0937x over previous
//
#include <hip/hip_runtime.h>
#include <hip/hip_bf16.h>
#include <stdint.h>

typedef __attribute__((ext_vector_type(4))) float f32x4;
typedef __attribute__((ext_vector_type(8))) short short8;
typedef __attribute__((ext_vector_type(4))) short short4v;

#define CDIV(a, b) (((a) + (b) - 1) / (b))

__device__ __forceinline__ unsigned short f2bf(float x) {
  union { float f; unsigned int u; } c; c.f = x;
  unsigned int r = c.u + 0x7FFFu + ((c.u >> 16) & 1u);   // round-to-nearest-even
  return (unsigned short)(r >> 16);
}
__device__ __forceinline__ unsigned short f2bf_hw(float x) {
  __hip_bfloat16 h = __float2bfloat16(x);                // pairs fuse into v_cvt_pk_bf16_f32
  unsigned short u; __builtin_memcpy(&u, &h, 2); return u;
}
__device__ __forceinline__ float bf2f(unsigned short b) {
  union { unsigned int u; float f; } c; c.u = (unsigned int)b << 16; return c.f;
}

// async global->LDS, 16B per lane; LDS dest must be wave-uniform base + lane*16 (linear)
__device__ __forceinline__ void gl2lds16(const void* g, void* lds) {
  __builtin_amdgcn_global_load_lds(
      reinterpret_cast<const __attribute__((address_space(1))) unsigned int*>(
          reinterpret_cast<uintptr_t>(g)),
      reinterpret_cast<__attribute__((address_space(3))) unsigned int*>(
          reinterpret_cast<uintptr_t>(lds)),
      16, 0, 0);
}

// ---------------- batched weight transpose: W[K][N] f32 -> Wt[N][Kpad] bf16, zero-padded ----
__device__ __forceinline__ void tr_tile(const float* __restrict__ W, unsigned short* __restrict__ Wt,
                                        int K, int N, int Kpad, int bx, int by) {
  __shared__ float tile[32][33];
  int kb = bx * 32, nb = by * 32;
  int tx = threadIdx.x & 31, ty = threadIdx.x >> 5;  // 256 threads = 32x8
  for (int r = ty; r < 32; r += 8) {
    int k = kb + r, n = nb + tx;
    tile[r][tx] = (k < K && n < N) ? W[(size_t)k * N + n] : 0.f;
  }
  __syncthreads();
  for (int r = ty; r < 32; r += 8) {
    int n = nb + r, k = kb + tx;
    if (n < N && k < Kpad) Wt[(size_t)n * Kpad + k] = f2bf(tile[tx][r]);
  }
}

// block-range -> job table (hardcoded, matches the 6 original launches exactly):
// [0,1504):   W_fc1 3000x512 -> Wt1 (Kpad 3008), grid 94x16
// [1504,2016): W_fc2 1024x512 -> Wt2,            grid 32x16
// [2016,2144): W_g11 512x256  -> Wt11,           grid 16x8
// [2144,2272): W_g12 512x256  -> Wt12,           grid 16x8
// [2272,2288): W_g21 256x64   -> WtC rows 0-63,  grid 8x2
// [2288,2304): W_g22 256x64   -> WtC rows 64-127,grid 8x2
__global__ __launch_bounds__(256)
void transpose_all(const float* __restrict__ Wfc1, unsigned short* __restrict__ Wt1,
                   const float* __restrict__ Wfc2, unsigned short* __restrict__ Wt2,
                   const float* __restrict__ Wg11, unsigned short* __restrict__ Wt11,
                   const float* __restrict__ Wg12, unsigned short* __restrict__ Wt12,
                   const float* __restrict__ Wg21, const float* __restrict__ Wg22,
                   unsigned short* __restrict__ WtC) {
  int b = blockIdx.x;
  if (b < 1504)      { tr_tile(Wfc1, Wt1, 3000, 512, 3008, b % 94, b / 94); }
  else if (b < 2016) { int r = b - 1504; tr_tile(Wfc2, Wt2, 1024, 512, 1024, r % 32, r / 32); }
  else if (b < 2144) { int r = b - 2016; tr_tile(Wg11, Wt11, 512, 256, 512, r % 16, r / 16); }
  else if (b < 2272) { int r = b - 2144; tr_tile(Wg12, Wt12, 512, 256, 512, r % 16, r / 16); }
  else if (b < 2288) { int r = b - 2272; tr_tile(Wg21, WtC, 256, 64, 256, r % 8, r / 8); }
  else               { int r = b - 2288; tr_tile(Wg22, WtC + (size_t)64 * 256, 256, 64, 256, r % 8, r / 8); }
}

// ---------------- graph prep ----------------
__global__ void prep_init(int* __restrict__ dA, int* __restrict__ dB,
                          int* __restrict__ cA, int* __restrict__ cB, int n) {
  int i = blockIdx.x * blockDim.x + threadIdx.x;
  if (i < n) { dA[i] = 1; dB[i] = 1; cA[i] = 0; cB[i] = 0; }   // deg=1 (self-loop), cursor=0
}

__global__ void dinv_both(const int* __restrict__ dA, float* __restrict__ vA,
                          const int* __restrict__ dB, float* __restrict__ vB, int n) {
  int i = blockIdx.x * blockDim.x + threadIdx.x;
  if (i < n) { vA[i] = rsqrtf((float)dA[i]); vB[i] = rsqrtf((float)dB[i]); }
}

// exclusive scan of (deg-1) -> row_ptr[0..n]; blockIdx.x selects graph
__global__ void scan_rowptr_dual(const int* __restrict__ degA, int* __restrict__ rpA,
                                 const int* __restrict__ degB, int* __restrict__ rpB, int n) {
  const int* deg = (blockIdx.x == 0) ? degA : degB;
  int* rp = (blockIdx.x == 0) ? rpA : rpB;
  __shared__ int wsum[16];
  __shared__ int carry_s;
  const int tid = threadIdx.x, lane = tid & 63, w = tid >> 6;
  if (tid == 0) carry_s = 0;
  __syncthreads();
  for (int base = 0; base < n; base += 1024) {
    int i = base + tid;
    int d = (i < n) ? (deg[i] - 1) : 0;
    int v = d;
    #pragma unroll
    for (int off = 1; off < 64; off <<= 1) {
      int t = __shfl_up(v, off, 64);
      if (lane >= off) v += t;
    }
    if (lane == 63) wsum[w] = v;
    __syncthreads();
    int carry = carry_s;
    if (w == 0) {
      int s = (lane < 16) ? wsum[lane] : 0;
      #pragma unroll
      for (int off = 1; off < 16; off <<= 1) {
        int t = __shfl_up(s, off, 64);
        if (lane >= off) s += t;
      }
      if (lane < 16) wsum[lane] = s;
    }
    __syncthreads();
    int woff = (w > 0) ? wsum[w - 1] : 0;
    if (i < n) rp[i] = carry + woff + v - d;
    if (tid == 0) carry_s = carry + wsum[15];
    __syncthreads();
  }
  if (threadIdx.x == 0) rp[n] = carry_s;
}

// prep args passed by value to gemm_pair tail blocks
struct PrepArgs {
  const int* eiA; int EA;
  const int* eiB; int EB;
  int n;
  int* degA; int* degB;                       // TAIL=1 (hist)
  const int* rpA; const int* rpB;             // TAIL=2 (fill)
  int* curA; int* curB;
  const float* dvA; const float* dvB;
  int* csA; float* cnA;
  int* csB; float* cnB;
};

// ---------------- gemm_pair: TWO independent GEMMs, CONCATENATED block ranges ----------------
// Blocks [0,split) = job0, [split,2*split) = job1 (split%8==0 -> bid%8 == HW XCD preserved).
// TAIL=1: blocks >= 2*split run deg-histogram for both graphs.
// TAIL=2: blocks >= 2*split run CSR fill for both graphs.
// Body = r8-proven gemm7. AMODE 1: A bf16 via gl2lds. AMODE 3: A f32 RAW via gl2lds,
// bf16 cvt at fragment read; K-tail reg-staged zero-masked (K%4==0).
template<int BM, int BN, int TH, int NT_N, int AMODE, int TAIL, bool ADD_BIAS, bool DO_RELU>
__global__ __launch_bounds__(TH, 2)
void gemm_pair(const void* __restrict__ A0, const unsigned short* __restrict__ Bt0,
               const float* __restrict__ b0, unsigned short* __restrict__ C0, int K0, int Kp0,
               const void* __restrict__ A1, const unsigned short* __restrict__ Bt1,
               const float* __restrict__ b1, unsigned short* __restrict__ C1, int K1, int Kp1,
               int split, int NT_M, int M, int N, PrepArgs pa) {
  constexpr int BK = 64;
  constexpr int WN = TH / 64;
  constexpr int WCOLS = BN / WN;
  constexpr int FM = BM / 16, FN = WCOLS / 16;
  constexpr int BIT  = (BN * 8) / TH;
  constexpr int AIT1 = (BM * 8) / TH;
  constexpr int AIT3 = (BM * 16) / TH;
  constexpr int LOGN = (NT_N == 4) ? 2 : (NT_N == 2 ? 1 : 0);

  const int bid0 = blockIdx.x;
  const int tid = threadIdx.x;

  if constexpr (TAIL != 0) {
    if (bid0 >= 2 * split) {                      // prep tail blocks
      int e = (bid0 - 2 * split) * TH + tid;
      if constexpr (TAIL == 1) {                  // deg histogram (both graphs)
        if (e < pa.EA) {
          unsigned int d = (unsigned int)pa.eiA[(size_t)pa.EA + e];
          if (d < (unsigned int)pa.n) atomicAdd(&pa.degA[d], 1);
        } else if (e < pa.EA + pa.EB) {
          int e2 = e - pa.EA;
          unsigned int d = (unsigned int)pa.eiB[(size_t)pa.EB + e2];
          if (d < (unsigned int)pa.n) atomicAdd(&pa.degB[d], 1);
        }
      } else {                                    // CSR fill (both graphs)
        if (e < pa.EA) {
          unsigned int s = (unsigned int)pa.eiA[e];
          unsigned int d = (unsigned int)pa.eiA[(size_t)pa.EA + e];
          if (s < (unsigned int)pa.n && d < (unsigned int)pa.n) {
            int pos = pa.rpA[d] + atomicAdd(&pa.curA[d], 1);
            pa.csA[pos] = (int)s;
            pa.cnA[pos] = pa.dvA[s] * pa.dvA[d];
          }
        } else if (e < pa.EA + pa.EB) {
          int e2 = e - pa.EA;
          unsigned int s = (unsigned int)pa.eiB[e2];
          unsigned int d = (unsigned int)pa.eiB[(size_t)pa.EB + e2];
          if (s < (unsigned int)pa.n && d < (unsigned int)pa.n) {
            int pos = pa.rpB[d] + atomicAdd(&pa.curB[d], 1);
            pa.csB[pos] = (int)s;
            pa.cnB[pos] = pa.dvB[s] * pa.dvB[d];
          }
        }
      }
      return;
    }
  }

  const bool j1 = (bid0 >= split);
  const int bid = j1 ? (bid0 - split) : bid0;
  const void* Av = j1 ? A1 : A0;
  const unsigned short* Bt = j1 ? Bt1 : Bt0;
  const float* bias = j1 ? b1 : b0;
  unsigned short* C = j1 ? C1 : C0;
  const int K = j1 ? K1 : K0;
  const int Kpad = j1 ? Kp1 : Kp0;

  const int xcd = bid & 7, j = bid >> 3;
  const int per = (NT_M + 7) >> 3;
  const int mt = xcd * per + (j >> LOGN);
  const int nt = j & (NT_N - 1);
  if (mt >= NT_M) return;
  const int gm = mt * BM, gn = nt * BN;

  constexpr int ABYTES = (AMODE == 3) ? BM * BK * 4 : BM * BK * 2;
  __shared__ __align__(16) char AldsRaw[ABYTES];
  __shared__ __align__(16) unsigned short Blds[BN * BK];

  const int wid = tid >> 6, lane = tid & 63;
  const int kg = lane >> 4, lr = lane & 15;
  const int sx = lr & 7;

  f32x4 acc[FM][FN] = {};

  const int nkt = Kpad / BK;
  for (int kt = 0; kt < nkt; ++kt) {
    const int k0 = kt * BK;
    // ---- stage A ----
    if constexpr (AMODE == 1) {
      const unsigned short* A = (const unsigned short*)Av;
      unsigned short* Alds = (unsigned short*)AldsRaw;
      #pragma unroll
      for (int it = 0; it < AIT1; ++it) {
        int q = it * TH + tid;
        int r = q >> 3, s = q & 7;
        int grow = gm + r; if (grow > M - 1) grow = M - 1;
        gl2lds16(A + (size_t)grow * K + k0 + ((s ^ (r & 7)) << 3), &Alds[q * 8]);
      }
    } else {  // AMODE 3: raw f32, 16 slots/row, swizzled source
      const float* A = (const float*)Av;
      float* Af = (float*)AldsRaw;
      if (k0 + BK <= K) {
        #pragma unroll
        for (int it = 0; it < AIT3; ++it) {
          int q = it * TH + tid;
          int r = q >> 4, s = q & 15;
          int grow = gm + r; if (grow > M - 1) grow = M - 1;
          gl2lds16(A + (size_t)grow * K + k0 + ((s ^ (r & 15)) << 2), &Af[q * 4]);
        }
      } else {  // tail (K%4==0): reg-staged, zero-masked
        #pragma unroll
        for (int it = 0; it < AIT3; ++it) {
          int q = it * TH + tid;
          int r = q >> 4, s = q & 15;
          int grow = gm + r; if (grow > M - 1) grow = M - 1;
          int kbase = k0 + ((s ^ (r & 15)) << 2);
          f32x4 v = {0.f, 0.f, 0.f, 0.f};
          if (kbase + 4 <= K) v = *(const f32x4*)(A + (size_t)grow * K + kbase);
          *(f32x4*)(&Af[q * 4]) = v;
        }
      }
    }
    // ---- stage B via gl2lds (linear dest, inverse-swizzled source) ----
    #pragma unroll
    for (int it = 0; it < BIT; ++it) {
      int q = it * TH + tid;
      int r = q >> 3, s = q & 7;
      gl2lds16(Bt + (size_t)(gn + r) * Kpad + k0 + ((s ^ (r & 7)) << 3), &Blds[q * 8]);
    }
    __syncthreads();
    // ---- fragments + MFMA (2 K-slices of 32) ----
    #pragma unroll
    for (int ks = 0; ks < 2; ++ks) {
      const int k8 = ks * 4 + kg;
      short8 af[FM];
      #pragma unroll
      for (int m = 0; m < FM; m++) {
        int r = m * 16 + lr;                 // r & 15 == lr
        if constexpr (AMODE == 1) {
          const unsigned short* Alds = (const unsigned short*)AldsRaw;
          af[m] = *(const short8*)(&Alds[(r * 8 + (k8 ^ sx)) * 8]);
        } else {
          const float* Af = (const float*)AldsRaw;
          int s0 = (2 * k8) ^ lr, s1 = (2 * k8 + 1) ^ lr;
          f32x4 lo = *(const f32x4*)(Af + r * 64 + s0 * 4);
          f32x4 hi = *(const f32x4*)(Af + r * 64 + s1 * 4);
          #pragma unroll
          for (int i = 0; i < 4; i++) {
            af[m][i]     = (short)f2bf_hw(lo[i]);
            af[m][i + 4] = (short)f2bf_hw(hi[i]);
          }
        }
      }
      #pragma unroll
      for (int n2 = 0; n2 < FN; n2++) {
        int cc = wid * WCOLS + n2 * 16 + lr;
        short8 bq = *(const short8*)(&Blds[(cc * 8 + (k8 ^ sx)) * 8]);
        #pragma unroll
        for (int m = 0; m < FM; m++)
          acc[m][n2] = __builtin_amdgcn_mfma_f32_16x16x32_bf16(af[m], bq, acc[m][n2], 0, 0, 0);
      }
    }
    __syncthreads();
  }
  // ---- epilogue: C/D layout col=lane&15, row=(lane>>4)*4+reg ----
  #pragma unroll
  for (int m = 0; m < FM; m++) {
    #pragma unroll
    for (int jj = 0; jj < 4; jj++) {
      int grow = gm + m * 16 + kg * 4 + jj;
      if (grow < M) {
        #pragma unroll
        for (int n2 = 0; n2 < FN; n2++) {
          int gcol = gn + wid * WCOLS + n2 * 16 + lr;
          float v = acc[m][n2][jj];
          if constexpr (ADD_BIAS) v += bias[gcol];
          if constexpr (DO_RELU) v = fmaxf(v, 0.f);
          C[(size_t)grow * N + gcol] = f2bf(v);
        }
      }
    }
  }
}

// ---------------- single-job GEMM (final layer), r8-proven config ----------------
template<int BM, int BN, int TH, int NT_N, int AMODE, bool ADD_BIAS, bool DO_RELU>
__global__ __launch_bounds__(TH, 2)
void gemm7(const void* __restrict__ Av, const unsigned short* __restrict__ Bt,
           const float* __restrict__ bias, unsigned short* __restrict__ C,
           int NT_M, int M, int N, int K, int Kpad) {
  constexpr int BK = 64;
  constexpr int WN = TH / 64;
  constexpr int WCOLS = BN / WN;
  constexpr int FM = BM / 16, FN = WCOLS / 16;
  constexpr int BIT  = (BN * 8) / TH;
  constexpr int AIT1 = (BM * 8) / TH;
  constexpr int LOGN = (NT_N == 2) ? 1 : 0;

  const int bid = blockIdx.x;
  const int xcd = bid & 7, j = bid >> 3;
  const int per = (NT_M + 7) >> 3;
  const int mt = xcd * per + (j >> LOGN);
  const int nt = j & (NT_N - 1);
  if (mt >= NT_M) return;
  const int gm = mt * BM, gn = nt * BN;

  __shared__ __align__(16) unsigned short Alds[BM * BK];
  __shared__ __align__(16) unsigned short Blds[BN * BK];

  const int tid = threadIdx.x;
  const int wid = tid >> 6, lane = tid & 63;
  const int kg = lane >> 4, lr = lane & 15;
  const int sx = lr & 7;

  f32x4 acc[FM][FN] = {};

  const int nkt = Kpad / BK;
  for (int kt = 0; kt < nkt; ++kt) {
    const int k0 = kt * BK;
    const unsigned short* A = (const unsigned short*)Av;
    #pragma unroll
    for (int it = 0; it < AIT1; ++it) {
      int q = it * TH + tid;
      int r = q >> 3, s = q & 7;
      int grow = gm + r; if (grow > M - 1) grow = M - 1;
      gl2lds16(A + (size_t)grow * K + k0 + ((s ^ (r & 7)) << 3), &Alds[q * 8]);
    }
    #pragma unroll
    for (int it = 0; it < BIT; ++it) {
      int q = it * TH + tid;
      int r = q >> 3, s = q & 7;
      gl2lds16(Bt + (size_t)(gn + r) * Kpad + k0 + ((s ^ (r & 7)) << 3), &Blds[q * 8]);
    }
    __syncthreads();
    #pragma unroll
    for (int ks = 0; ks < 2; ++ks) {
      const int k8 = ks * 4 + kg;
      short8 af[FM];
      #pragma unroll
      for (int m = 0; m < FM; m++) {
        int r = m * 16 + lr;
        af[m] = *(const short8*)(&Alds[(r * 8 + (k8 ^ sx)) * 8]);
      }
      #pragma unroll
      for (int n2 = 0; n2 < FN; n2++) {
        int cc = wid * WCOLS + n2 * 16 + lr;
        short8 bq = *(const short8*)(&Blds[(cc * 8 + (k8 ^ sx)) * 8]);
        #pragma unroll
        for (int m = 0; m < FM; m++)
          acc[m][n2] = __builtin_amdgcn_mfma_f32_16x16x32_bf16(af[m], bq, acc[m][n2], 0, 0, 0);
      }
    }
    __syncthreads();
  }
  #pragma unroll
  for (int m = 0; m < FM; m++) {
    #pragma unroll
    for (int jj = 0; jj < 4; jj++) {
      int grow = gm + m * 16 + kg * 4 + jj;
      if (grow < M) {
        #pragma unroll
        for (int n2 = 0; n2 < FN; n2++) {
          int gcol = gn + wid * WCOLS + n2 * 16 + lr;
          float v = acc[m][n2][jj];
          if constexpr (ADD_BIAS) v += bias[gcol];
          if constexpr (DO_RELU) v = fmaxf(v, 0.f);
          C[(size_t)grow * N + gcol] = f2bf(v);
        }
      }
    }
  }
}

// ---------------- per-graph GCN gather: 4-way unrolled edge loop ----------------
template<int LDH>
__device__ __forceinline__ f32x4 gcn_gather(const unsigned short* __restrict__ h,
                                            const int* __restrict__ rp,
                                            const int* __restrict__ cs,
                                            const float* __restrict__ cn,
                                            const float* __restrict__ dv,
                                            int node, int c4) {
  float d = dv[node];
  float sc = d * d;
  f32x4 a0, a1 = {0.f,0.f,0.f,0.f}, a2 = {0.f,0.f,0.f,0.f}, a3 = {0.f,0.f,0.f,0.f};
  {
    short4v v = *(const short4v*)(h + (size_t)node * LDH + c4);
    a0[0] = sc * bf2f((unsigned short)v[0]);
    a0[1] = sc * bf2f((unsigned short)v[1]);
    a0[2] = sc * bf2f((unsigned short)v[2]);
    a0[3] = sc * bf2f((unsigned short)v[3]);
  }
  int e = rp[node];
  const int e1 = rp[node + 1];
  for (; e + 4 <= e1; e += 4) {               // 4 independent gathers in flight
    int s0 = cs[e], s1 = cs[e+1], s2 = cs[e+2], s3 = cs[e+3];
    float n0 = cn[e], n1 = cn[e+1], n2 = cn[e+2], n3 = cn[e+3];
    short4v v0 = *(const short4v*)(h + (size_t)s0 * LDH + c4);
    short4v v1 = *(const short4v*)(h + (size_t)s1 * LDH + c4);
    short4v v2 = *(const short4v*)(h + (size_t)s2 * LDH + c4);
    short4v v3 = *(const short4v*)(h + (size_t)s3 * LDH + c4);
    #pragma unroll
    for (int i = 0; i < 4; i++) {
      a0[i] += n0 * bf2f((unsigned short)v0[i]);
      a1[i] += n1 * bf2f((unsigned short)v1[i]);
      a2[i] += n2 * bf2f((unsigned short)v2[i]);
      a3[i] += n3 * bf2f((unsigned short)v3[i]);
    }
  }
  for (; e < e1; ++e) {
    int s0 = cs[e]; float n0 = cn[e];
    short4v v0 = *(const short4v*)(h + (size_t)s0 * LDH + c4);
    #pragma unroll
    for (int i = 0; i < 4; i++) a0[i] += n0 * bf2f((unsigned short)v0[i]);
  }
  #pragma unroll
  for (int i = 0; i < 4; i++) a0[i] += a1[i] + a2[i] + a3[i];
  return a0;
}

// ---------------- fused dual-graph GCN scatter ----------------
// out = w * act(gcnA(hA)+bA) + (1-w) * act(gcnB(hB)+bB), act = relu or identity.
template<int F, int LDHA, int LDHB, bool DO_RELU, bool OUT_BF16>
__global__ __launch_bounds__(256)
void scatter_fused(const unsigned short* __restrict__ hA, const unsigned short* __restrict__ hB,
                   const int* __restrict__ rpA, const int* __restrict__ csA,
                   const float* __restrict__ cnA, const float* __restrict__ dvA,
                   const float* __restrict__ bA,
                   const int* __restrict__ rpB, const int* __restrict__ csB,
                   const float* __restrict__ cnB, const float* __restrict__ dvB,
                   const float* __restrict__ bB,
                   const float* __restrict__ wptr, void* __restrict__ outp, int n) {
  constexpr int TPN = F / 4;
  const int tid = threadIdx.x;
  const int node = blockIdx.x * (256 / TPN) + tid / TPN;
  const int c4 = (tid % TPN) * 4;
  if (node >= n) return;

  f32x4 accA = gcn_gather<LDHA>(hA, rpA, csA, cnA, dvA, node, c4);
  f32x4 accB = gcn_gather<LDHB>(hB, rpB, csB, cnB, dvB, node, c4);

  f32x4 bvA = *(const f32x4*)(bA + c4);
  f32x4 bvB = *(const f32x4*)(bB + c4);
  float w = *wptr;
  size_t idx = (size_t)node * F + c4;
  f32x4 r;
  #pragma unroll
  for (int i = 0; i < 4; i++) {
    float va = accA[i] + bvA[i];
    float vb = accB[i] + bvB[i];
    if constexpr (DO_RELU) { va = fmaxf(va, 0.f); vb = fmaxf(vb, 0.f); }
    r[i] = w * va + (1.f - w) * vb;
  }
  if constexpr (OUT_BF16) {
    short4v o;
    o[0] = (short)f2bf(r[0]); o[1] = (short)f2bf(r[1]);
    o[2] = (short)f2bf(r[2]); o[3] = (short)f2bf(r[3]);
    *(short4v*)((unsigned short*)outp + idx) = o;
  } else {
    *(f32x4*)((float*)outp + idx) = r;
  }
}

// ---------------- host ----------------
extern "C" void kernel_launch(void* const* d_in, const int* in_sizes, int n_in,
                              void* d_out, int out_size, void* d_ws, size_t ws_size,
                              hipStream_t stream) {
  const float* gene  = (const float*)d_in[0];
  const float* img   = (const float*)d_in[1];
  const int* ei_ge = (const int*)d_in[2];   // integers arrive as int32
  const int* ei_sp = (const int*)d_in[3];
  const float* W_fc1 = (const float*)d_in[4];  const float* b_fc1 = (const float*)d_in[5];
  const float* W_fc2 = (const float*)d_in[6];  const float* b_fc2 = (const float*)d_in[7];
  const float* W_g11 = (const float*)d_in[8];  const float* b_g11 = (const float*)d_in[9];
  const float* W_g12 = (const float*)d_in[10]; const float* b_g12 = (const float*)d_in[11];
  const float* W_g21 = (const float*)d_in[12]; const float* b_g21 = (const float*)d_in[13];
  const float* W_g22 = (const float*)d_in[14]; const float* b_g22 = (const float*)d_in[15];
  const float* w1p   = (const float*)d_in[16];
  const float* w2p   = (const float*)d_in[17];

  const int Nn = 50000;
  const int E_ge = in_sizes[2] / 2;
  const int E_sp = in_sizes[3] / 2;
  const int NT_M = CDIV(Nn, 64);             // 782 M-tiles of 64
  const int PER  = CDIV(NT_M, 8);            // 98
  const int G1   = 8 * PER;                  // 784 (NT_N=1), % 8 == 0
  const int G2   = 8 * PER * 2;              // 1568 (NT_N=2), % 8 == 0
  const int TB   = CDIV(E_sp + E_ge, 256);   // prep tail blocks

  char* ws = (char*)d_ws;
  size_t off = 0;
  auto alloc = [&](size_t bytes) -> void* {
    void* p = ws + off;
    off += (bytes + 255) & ~(size_t)255;
    return p;
  };

  unsigned short* Wt1  = (unsigned short*)alloc((size_t)512 * 3008 * 2);
  unsigned short* Wt2  = (unsigned short*)alloc((size_t)512 * 1024 * 2);
  unsigned short* Wt11 = (unsigned short*)alloc((size_t)256 * 512 * 2);
  unsigned short* Wt12 = (unsigned short*)alloc((size_t)256 * 512 * 2);
  unsigned short* WtC  = (unsigned short*)alloc((size_t)128 * 256 * 2);  // [W_g21 | W_g22] rows
  int*   deg_sp  = (int*)alloc((size_t)Nn * 4);
  int*   deg_ge  = (int*)alloc((size_t)Nn * 4);
  float* dinv_sp = (float*)alloc((size_t)Nn * 4);
  float* dinv_ge = (float*)alloc((size_t)Nn * 4);
  int*   rp_sp   = (int*)alloc((size_t)(Nn + 1) * 4);
  int*   rp_ge   = (int*)alloc((size_t)(Nn + 1) * 4);
  int*   cur_sp  = (int*)alloc((size_t)Nn * 4);
  int*   cur_ge  = (int*)alloc((size_t)Nn * 4);
  int*   csrc_sp = (int*)alloc((size_t)E_sp * 4);
  float* cnrm_sp = (float*)alloc((size_t)E_sp * 4);
  int*   csrc_ge = (int*)alloc((size_t)E_ge * 4);
  float* cnrm_ge = (float*)alloc((size_t)E_ge * 4);
  unsigned short* xbuf1 = (unsigned short*)alloc((size_t)Nn * 512 * 2);  // x1 / Xc
  unsigned short* xbuf2 = (unsigned short*)alloc((size_t)Nn * 512 * 2);  // x2
  unsigned short* tmpA  = (unsigned short*)alloc((size_t)Nn * 256 * 2);  // g11 out; later tmp2
  unsigned short* tmpB  = (unsigned short*)alloc((size_t)Nn * 256 * 2);  // g12 out
  unsigned short* Xc    = xbuf1;
  unsigned short* tmp2  = tmpA;
  (void)ws_size; (void)n_in; (void)out_size;

  PrepArgs pa;
  pa.eiA = ei_sp; pa.EA = E_sp;
  pa.eiB = ei_ge; pa.EB = E_ge;
  pa.n = Nn;
  pa.degA = deg_sp; pa.degB = deg_ge;
  pa.rpA = rp_sp; pa.rpB = rp_ge;
  pa.curA = cur_sp; pa.curB = cur_ge;
  pa.dvA = dinv_sp; pa.dvB = dinv_ge;
  pa.csA = csrc_sp; pa.cnA = cnrm_sp;
  pa.csB = csrc_ge; pa.cnB = cnrm_ge;

  // 1. all weight transposes in one launch (bf16, K zero-padded)
  transpose_all<<<2304, 256, 0, stream>>>(W_fc1, Wt1, W_fc2, Wt2,
                                          W_g11, Wt11, W_g12, Wt12,
                                          W_g21, W_g22, WtC);

  // 2. deg/cursor init (must precede hist tail in step 3)
  prep_init<<<CDIV(Nn, 256), 256, 0, stream>>>(deg_sp, deg_ge, cur_sp, cur_ge, Nn);

  // 3. FC1 + FC2 + deg-histogram in one launch (concatenated; tail = hist):
  //    x1 = relu(gene@W1+b) ; x2 = relu(img@W2+b)
  gemm_pair<64, 256, 256, 2, 3, 1, true, true><<<2 * G2 + TB, 256, 0, stream>>>(
      gene, Wt1, b_fc1, xbuf1, 3000, 3008,
      img,  Wt2, b_fc2, xbuf2, 1024, 1024,
      G2, NT_M, Nn, 512, pa);

  // 4. dinv + row_ptr scan (consume deg from step 3)
  dinv_both<<<CDIV(Nn, 256), 256, 0, stream>>>(deg_sp, dinv_sp, deg_ge, dinv_ge, Nn);
  scan_rowptr_dual<<<2, 1024, 0, stream>>>(deg_sp, rp_sp, deg_ge, rp_ge, Nn);

  // 5. mids + CSR fill in one launch (tail = fill): tmpA = x1@W_g11 ; tmpB = x2@W_g12
  gemm_pair<64, 256, 256, 1, 1, 2, false, false><<<2 * G1 + TB, 256, 0, stream>>>(
      xbuf1, Wt11, nullptr, tmpA, 512, 512,
      xbuf2, Wt12, nullptr, tmpB, 512, 512,
      G1, NT_M, Nn, 256, pa);

  // 6. Xc = bf16( w1*relu(gcn_sp(tmpA)+b_g11) + (1-w1)*relu(gcn_ge(tmpB)+b_g12) )
  scatter_fused<256, 256, 256, true, true><<<Nn / 4, 256, 0, stream>>>(
      tmpA, tmpB, rp_sp, csrc_sp, cnrm_sp, dinv_sp, b_g11,
      rp_ge, csrc_ge, cnrm_ge, dinv_ge, b_g12, w1p, Xc, Nn);

  // 7. tmp2 = Xc @ [W_g21 | W_g22]  (N=128, one pass; tmp2 aliases tmpA)
  gemm7<64, 128, 256, 1, 1, false, false><<<G1, 256, 0, stream>>>(
      Xc, WtC, nullptr, tmp2, NT_M, Nn, 128, 256, 256);

  // 8. d_out = w2*(gcn_sp(tmp2[:,0:64])+b_g21) + (1-w2)*(gcn_ge(tmp2[:,64:128])+b_g22)
  scatter_fused<64, 128, 128, false, false><<<Nn / 16, 256, 0, stream>>>(
      tmp2, tmp2 + 64, rp_sp, csrc_sp, cnrm_sp, dinv_sp, b_g21,
      rp_ge, csrc_ge, cnrm_ge, dinv_ge, b_g22, w2p, d_out, Nn);
}